// Round 2
// baseline (155.599 us; speedup 1.0000x reference)
//
#include <hip/hip_runtime.h>

// PhobiaLoss: YOLO-style loss over (B=256, 52, 52, 20) fp32 tensors -> scalar.
// Round 2: fix coalescing. Old kernel loaded per-cell float4s at 80B lane
// stride (transaction-bound, 384 GB/s). Now each 256-thread block stages its
// 256 cells (1280 float4s, contiguous) via fully-coalesced loads + LDS
// transpose (stride 17 floats: gcd(17,32)=1 -> conflict-free re-read).

constexpr int   kB        = 256;
constexpr int   kGrid     = 52;
constexpr int   kCells    = kB * kGrid * kGrid;   // 692224 = 2704 * 256 exactly
constexpr float kAlpha    = 0.25f;
constexpr float kLamCoord = 5.0f;

constexpr int kStride = 17;                       // floats per cell in LDS (16 + 1 pad)

__device__ __forceinline__ void stage_and_read(const float4* __restrict__ src4,
                                               int base4, int tid,
                                               float* lds, float (&out)[16])
{
    // Coalesced: 5 wave-contiguous float4 loads covering the block's 1280 float4s.
    const float4 r0 = src4[base4 + tid];
    const float4 r1 = src4[base4 + 256  + tid];
    const float4 r2 = src4[base4 + 512  + tid];
    const float4 r3 = src4[base4 + 768  + tid];
    const float4 r4 = src4[base4 + 1024 + tid];

    // Scatter channels 0..15 of each cell into LDS (skip the 5th float4 of
    // each cell = channels 16..19, which the loss never reads).
    #pragma unroll
    for (int k = 0; k < 5; ++k) {
        const int f    = k * 256 + tid;       // flat float4 index within block
        const int cell = f / 5;               // compiler magic-div
        const int rem  = f - cell * 5;
        if (rem != 4) {
            const float4 v = (k == 0) ? r0 : (k == 1) ? r1 : (k == 2) ? r2
                           : (k == 3) ? r3 : r4;
            const int a = cell * kStride + rem * 4;
            lds[a + 0] = v.x; lds[a + 1] = v.y;
            lds[a + 2] = v.z; lds[a + 3] = v.w;
        }
    }
    __syncthreads();

    // Conflict-free gather: addr = tid*17 + j, 17 odd -> 2 lanes/bank (free).
    #pragma unroll
    for (int j = 0; j < 16; ++j) out[j] = lds[tid * kStride + j];
}

__global__ __launch_bounds__(256) void phobia_main_kernel(
    const float4* __restrict__ pred4,
    const float4* __restrict__ tgt4,
    float* __restrict__ acc)   // acc[0]=coord, acc[1]=conf, acc[2]=cls, acc[3]=nobj
{
    __shared__ float lds[256 * kStride];   // 17408 B
    __shared__ float sred[4][4];

    const int tid   = threadIdx.x;
    const int base4 = blockIdx.x * 1280;

    float p[16], t[16];
    stage_and_read(pred4, base4, tid, lds, p);
    __syncthreads();                       // reads done before tgt overwrites
    stage_and_read(tgt4, base4, tid, lds, t);

    float coord = 0.f, conf = 0.f, cls = 0.f;

    float obj_count = 0.f;
    #pragma unroll
    for (int n = 0; n < 2; ++n) {
        const int b5    = n * 5;
        const float l   = p[b5 + 4];      // conf logit
        const float tc  = t[b5 + 4];      // conf target
        const float has = (tc > 0.5f) ? 1.f : 0.f;

        float sq = 0.f;
        #pragma unroll
        for (int k = 0; k < 4; ++k) {
            const float d = p[b5 + k] - t[b5 + k];
            sq += d * d;
        }
        coord += has * sq;

        // focal BCE on confidence
        const float ce = fmaxf(l, 0.f) - l * tc + log1pf(__expf(-fabsf(l)));
        const float s  = 1.f / (1.f + __expf(-l));
        const float pt = s * tc + (1.f - s) * (1.f - tc);
        const float at = kAlpha * tc + (1.f - kAlpha) * (1.f - tc);
        const float om = 1.f - pt;
        conf += at * om * om * ce;

        obj_count += has;
    }

    // class NLL: argmax of target channels 10..14 (strict > = first-max),
    // carry the matching pred logit so all register indices stay static.
    float bv = t[10], pv = p[10];
    if (t[11] > bv) { bv = t[11]; pv = p[11]; }
    if (t[12] > bv) { bv = t[12]; pv = p[12]; }
    if (t[13] > bv) { bv = t[13]; pv = p[13]; }
    if (t[14] > bv) { bv = t[14]; pv = p[14]; }

    const float m  = fmaxf(fmaxf(fmaxf(p[10], p[11]), fmaxf(p[12], p[13])), p[14]);
    const float se = __expf(p[10] - m) + __expf(p[11] - m) + __expf(p[12] - m)
                   + __expf(p[13] - m) + __expf(p[14] - m);
    cls = obj_count * (__logf(se) + m - pv);

    float nobj = obj_count;

    // Wave-level reduce (64 lanes)
    #pragma unroll
    for (int off = 32; off >= 1; off >>= 1) {
        coord += __shfl_down(coord, off);
        conf  += __shfl_down(conf,  off);
        cls   += __shfl_down(cls,   off);
        nobj  += __shfl_down(nobj,  off);
    }

    const int wave = tid >> 6;
    const int lane = tid & 63;
    if (lane == 0) {
        sred[wave][0] = coord; sred[wave][1] = conf;
        sred[wave][2] = cls;   sred[wave][3] = nobj;
    }
    __syncthreads();
    if (tid == 0) {
        float c0 = 0.f, c1 = 0.f, c2 = 0.f, c3 = 0.f;
        #pragma unroll
        for (int w = 0; w < 4; ++w) {
            c0 += sred[w][0]; c1 += sred[w][1];
            c2 += sred[w][2]; c3 += sred[w][3];
        }
        atomicAdd(&acc[0], c0);
        atomicAdd(&acc[1], c1);
        atomicAdd(&acc[2], c2);
        atomicAdd(&acc[3], c3);
    }
}

__global__ void phobia_final_kernel(const float* __restrict__ acc,
                                    float* __restrict__ out)
{
    out[0] = kLamCoord * (acc[0] / (float)kB)
           + (acc[1] / (float)kB)
           + acc[2] / fmaxf(acc[3], 1.f);
}

extern "C" void kernel_launch(void* const* d_in, const int* in_sizes, int n_in,
                              void* d_out, int out_size, void* d_ws, size_t ws_size,
                              hipStream_t stream) {
    const float4* pred4 = (const float4*)d_in[0];
    const float4* tgt4  = (const float4*)d_in[1];
    float* acc = (float*)d_ws;
    float* out = (float*)d_out;

    hipMemsetAsync(acc, 0, 4 * sizeof(float), stream);

    const int blocks = kCells / 256;   // 2704, exact
    phobia_main_kernel<<<blocks, 256, 0, stream>>>(pred4, tgt4, acc);
    phobia_final_kernel<<<1, 1, 0, stream>>>(acc, out);
}

// Round 3
// 28.365 us; speedup vs baseline: 5.4856x; 5.4856x over previous
//
#include <hip/hip_runtime.h>

// PhobiaLoss: YOLO-style loss over (B=256, 52, 52, 20) fp32 tensors -> scalar.
// Round 3: remove the contended atomics. Rounds 0/1 both ran ~149us regardless
// of memory pattern (even with inputs fully L3-resident) -> bound by 10816
// same-line atomicAdds serializing at the coherence point. Now each block
// writes one float4 partial to its own d_ws slot; a tiny second kernel
// reduces 2704 partials and emits the scalar.

constexpr int   kB        = 256;
constexpr int   kGrid     = 52;
constexpr int   kCells    = kB * kGrid * kGrid;   // 692224 = 2704 * 256 exactly
constexpr int   kBlocks   = kCells / 256;         // 2704
constexpr float kAlpha    = 0.25f;
constexpr float kLamCoord = 5.0f;

constexpr int kStride = 17;                       // floats per cell in LDS (16 + 1 pad)

__device__ __forceinline__ void stage_and_read(const float4* __restrict__ src4,
                                               int base4, int tid,
                                               float* lds, float (&out)[16])
{
    // Coalesced: 5 wave-contiguous float4 loads covering the block's 1280 float4s.
    const float4 r0 = src4[base4 + tid];
    const float4 r1 = src4[base4 + 256  + tid];
    const float4 r2 = src4[base4 + 512  + tid];
    const float4 r3 = src4[base4 + 768  + tid];
    const float4 r4 = src4[base4 + 1024 + tid];

    // Scatter channels 0..15 of each cell into LDS (skip the 5th float4 of
    // each cell = channels 16..19, which the loss never reads).
    #pragma unroll
    for (int k = 0; k < 5; ++k) {
        const int f    = k * 256 + tid;       // flat float4 index within block
        const int cell = f / 5;               // compiler magic-div
        const int rem  = f - cell * 5;
        if (rem != 4) {
            const float4 v = (k == 0) ? r0 : (k == 1) ? r1 : (k == 2) ? r2
                           : (k == 3) ? r3 : r4;
            const int a = cell * kStride + rem * 4;
            lds[a + 0] = v.x; lds[a + 1] = v.y;
            lds[a + 2] = v.z; lds[a + 3] = v.w;
        }
    }
    __syncthreads();

    // Conflict-free gather: addr = tid*17 + j, 17 odd -> 2 lanes/bank (free).
    #pragma unroll
    for (int j = 0; j < 16; ++j) out[j] = lds[tid * kStride + j];
}

__global__ __launch_bounds__(256) void phobia_main_kernel(
    const float4* __restrict__ pred4,
    const float4* __restrict__ tgt4,
    float4* __restrict__ part)   // part[block] = {coord, conf, cls, nobj}
{
    __shared__ float lds[256 * kStride];   // 17408 B
    __shared__ float sred[4][4];

    const int tid   = threadIdx.x;
    const int base4 = blockIdx.x * 1280;

    float p[16], t[16];
    stage_and_read(pred4, base4, tid, lds, p);
    __syncthreads();                       // reads done before tgt overwrites
    stage_and_read(tgt4, base4, tid, lds, t);

    float coord = 0.f, conf = 0.f, cls = 0.f;

    float obj_count = 0.f;
    #pragma unroll
    for (int n = 0; n < 2; ++n) {
        const int b5    = n * 5;
        const float l   = p[b5 + 4];      // conf logit
        const float tc  = t[b5 + 4];      // conf target
        const float has = (tc > 0.5f) ? 1.f : 0.f;

        float sq = 0.f;
        #pragma unroll
        for (int k = 0; k < 4; ++k) {
            const float d = p[b5 + k] - t[b5 + k];
            sq += d * d;
        }
        coord += has * sq;

        // focal BCE on confidence
        const float ce = fmaxf(l, 0.f) - l * tc + log1pf(__expf(-fabsf(l)));
        const float s  = 1.f / (1.f + __expf(-l));
        const float pt = s * tc + (1.f - s) * (1.f - tc);
        const float at = kAlpha * tc + (1.f - kAlpha) * (1.f - tc);
        const float om = 1.f - pt;
        conf += at * om * om * ce;

        obj_count += has;
    }

    // class NLL: argmax of target channels 10..14 (strict > = first-max),
    // carry the matching pred logit so all register indices stay static.
    float bv = t[10], pv = p[10];
    if (t[11] > bv) { bv = t[11]; pv = p[11]; }
    if (t[12] > bv) { bv = t[12]; pv = p[12]; }
    if (t[13] > bv) { bv = t[13]; pv = p[13]; }
    if (t[14] > bv) { bv = t[14]; pv = p[14]; }

    const float m  = fmaxf(fmaxf(fmaxf(p[10], p[11]), fmaxf(p[12], p[13])), p[14]);
    const float se = __expf(p[10] - m) + __expf(p[11] - m) + __expf(p[12] - m)
                   + __expf(p[13] - m) + __expf(p[14] - m);
    cls = obj_count * (__logf(se) + m - pv);

    float nobj = obj_count;

    // Wave-level reduce (64 lanes)
    #pragma unroll
    for (int off = 32; off >= 1; off >>= 1) {
        coord += __shfl_down(coord, off);
        conf  += __shfl_down(conf,  off);
        cls   += __shfl_down(cls,   off);
        nobj  += __shfl_down(nobj,  off);
    }

    const int wave = tid >> 6;
    const int lane = tid & 63;
    if (lane == 0) {
        sred[wave][0] = coord; sred[wave][1] = conf;
        sred[wave][2] = cls;   sred[wave][3] = nobj;
    }
    __syncthreads();
    if (tid == 0) {
        float4 o;
        o.x = sred[0][0] + sred[1][0] + sred[2][0] + sred[3][0];
        o.y = sred[0][1] + sred[1][1] + sred[2][1] + sred[3][1];
        o.z = sred[0][2] + sred[1][2] + sred[2][2] + sred[3][2];
        o.w = sred[0][3] + sred[1][3] + sred[2][3] + sred[3][3];
        part[blockIdx.x] = o;   // distinct address per block: no contention
    }
}

__global__ __launch_bounds__(256) void phobia_reduce_kernel(
    const float4* __restrict__ part, float* __restrict__ out)
{
    const int tid = threadIdx.x;
    float c0 = 0.f, c1 = 0.f, c2 = 0.f, c3 = 0.f;
    for (int i = tid; i < kBlocks; i += 256) {
        const float4 v = part[i];
        c0 += v.x; c1 += v.y; c2 += v.z; c3 += v.w;
    }
    #pragma unroll
    for (int off = 32; off >= 1; off >>= 1) {
        c0 += __shfl_down(c0, off);
        c1 += __shfl_down(c1, off);
        c2 += __shfl_down(c2, off);
        c3 += __shfl_down(c3, off);
    }
    __shared__ float sred[4][4];
    const int wave = tid >> 6;
    const int lane = tid & 63;
    if (lane == 0) {
        sred[wave][0] = c0; sred[wave][1] = c1;
        sred[wave][2] = c2; sred[wave][3] = c3;
    }
    __syncthreads();
    if (tid == 0) {
        const float coord = sred[0][0] + sred[1][0] + sred[2][0] + sred[3][0];
        const float conf  = sred[0][1] + sred[1][1] + sred[2][1] + sred[3][1];
        const float cls   = sred[0][2] + sred[1][2] + sred[2][2] + sred[3][2];
        const float nobj  = sred[0][3] + sred[1][3] + sred[2][3] + sred[3][3];
        out[0] = kLamCoord * (coord / (float)kB)
               + (conf / (float)kB)
               + cls / fmaxf(nobj, 1.f);
    }
}

extern "C" void kernel_launch(void* const* d_in, const int* in_sizes, int n_in,
                              void* d_out, int out_size, void* d_ws, size_t ws_size,
                              hipStream_t stream) {
    const float4* pred4 = (const float4*)d_in[0];
    const float4* tgt4  = (const float4*)d_in[1];
    float4* part = (float4*)d_ws;          // kBlocks * 16 B = 43,264 B
    float* out = (float*)d_out;

    phobia_main_kernel<<<kBlocks, 256, 0, stream>>>(pred4, tgt4, part);
    phobia_reduce_kernel<<<1, 256, 0, stream>>>(part, out);
}

// Round 4
// 27.283 us; speedup vs baseline: 5.7032x; 1.0397x over previous
//
#include <hip/hip_runtime.h>

// PhobiaLoss: YOLO-style loss over (B=256, 52, 52, 20) fp32 tensors -> scalar.
// Round 4: single-exposure latency + HW staging.
//  - The LDS layout needed is a LINEAR copy of the block's 1280 float4s
//    (gather at tid*5+c is conflict-free: gcd(5,8)=1 across bank-quads), so
//    use __builtin_amdgcn_global_load_lds (dwordx4) -- no VGPR round-trip,
//    no scatter math, no ds_writes, zero bank conflicts.
//  - Both tensors staged into separate LDS buffers; all 10 loads issued
//    before ONE __syncthreads -> memory latency exposed once per block.
//  - Block partials to distinct d_ws slots (R3 fix); tiny reduce kernel.

constexpr int   kB        = 256;
constexpr int   kGrid     = 52;
constexpr int   kCells    = kB * kGrid * kGrid;   // 692224 = 2704 * 256 exactly
constexpr int   kBlocks   = kCells / 256;         // 2704
constexpr float kAlpha    = 0.25f;
constexpr float kLamCoord = 5.0f;

#define AS1(p) ((const __attribute__((address_space(1))) void*)(p))
#define AS3(p) ((__attribute__((address_space(3))) void*)(p))

__global__ __launch_bounds__(256) void phobia_main_kernel(
    const float4* __restrict__ pred4,
    const float4* __restrict__ tgt4,
    float4* __restrict__ part)   // part[block] = {coord, conf, cls, nobj}
{
    __shared__ float4 ldsP[1280];   // 20480 B: linear copy of block's pred
    __shared__ float4 ldsT[1280];   // 20480 B: linear copy of block's tgt
    __shared__ float  sred[4][4];

    const int tid  = threadIdx.x;
    const int wave = tid >> 6;
    const int lane = tid & 63;
    const size_t base4 = (size_t)blockIdx.x * 1280;

    // Issue all 10 direct global->LDS dwordx4 loads (coalesced, linear dest:
    // HW writes lds_base + lane*16, matching f = k*256 + wave*64 + lane).
    #pragma unroll
    for (int k = 0; k < 5; ++k) {
        const int f  = k * 256 + tid;          // per-lane float4 index
        const int fw = k * 256 + wave * 64;    // wave-uniform LDS base index
        __builtin_amdgcn_global_load_lds(AS1(pred4 + base4 + f), AS3(ldsP + fw), 16, 0, 0);
        __builtin_amdgcn_global_load_lds(AS1(tgt4  + base4 + f), AS3(ldsT + fw), 16, 0, 0);
    }
    __syncthreads();   // vmcnt(0) drain + barrier: LDS copies complete

    // Conflict-free gather: float4 addr tid*5+c, stride 5 -> all 8 bank-quads.
    const float4 P0 = ldsP[tid * 5 + 0], P1 = ldsP[tid * 5 + 1];
    const float4 P2 = ldsP[tid * 5 + 2], P3 = ldsP[tid * 5 + 3];
    const float4 T0 = ldsT[tid * 5 + 0], T1 = ldsT[tid * 5 + 1];
    const float4 T2 = ldsT[tid * 5 + 2], T3 = ldsT[tid * 5 + 3];

    const float p[16] = {P0.x, P0.y, P0.z, P0.w,  P1.x, P1.y, P1.z, P1.w,
                         P2.x, P2.y, P2.z, P2.w,  P3.x, P3.y, P3.z, P3.w};
    const float t[16] = {T0.x, T0.y, T0.z, T0.w,  T1.x, T1.y, T1.z, T1.w,
                         T2.x, T2.y, T2.z, T2.w,  T3.x, T3.y, T3.z, T3.w};

    float coord = 0.f, conf = 0.f;
    float obj_count = 0.f;
    #pragma unroll
    for (int n = 0; n < 2; ++n) {
        const int b5    = n * 5;
        const float l   = p[b5 + 4];      // conf logit
        const float tc  = t[b5 + 4];      // conf target
        const float has = (tc > 0.5f) ? 1.f : 0.f;

        float sq = 0.f;
        #pragma unroll
        for (int k = 0; k < 4; ++k) {
            const float d = p[b5 + k] - t[b5 + k];
            sq += d * d;
        }
        coord += has * sq;

        // focal BCE on confidence
        const float ce = fmaxf(l, 0.f) - l * tc + log1pf(__expf(-fabsf(l)));
        const float s  = 1.f / (1.f + __expf(-l));
        const float pt = s * tc + (1.f - s) * (1.f - tc);
        const float at = kAlpha * tc + (1.f - kAlpha) * (1.f - tc);
        const float om = 1.f - pt;
        conf += at * om * om * ce;

        obj_count += has;
    }

    // class NLL: argmax of target channels 10..14 (strict > = first-max),
    // carry the matching pred logit so all register indices stay static.
    float bv = t[10], pv = p[10];
    if (t[11] > bv) { bv = t[11]; pv = p[11]; }
    if (t[12] > bv) { bv = t[12]; pv = p[12]; }
    if (t[13] > bv) { bv = t[13]; pv = p[13]; }
    if (t[14] > bv) { bv = t[14]; pv = p[14]; }

    const float m  = fmaxf(fmaxf(fmaxf(p[10], p[11]), fmaxf(p[12], p[13])), p[14]);
    const float se = __expf(p[10] - m) + __expf(p[11] - m) + __expf(p[12] - m)
                   + __expf(p[13] - m) + __expf(p[14] - m);
    const float cls0 = obj_count * (__logf(se) + m - pv);

    float cls  = cls0;
    float nobj = obj_count;

    // Wave-level reduce (64 lanes)
    #pragma unroll
    for (int off = 32; off >= 1; off >>= 1) {
        coord += __shfl_down(coord, off);
        conf  += __shfl_down(conf,  off);
        cls   += __shfl_down(cls,   off);
        nobj  += __shfl_down(nobj,  off);
    }

    if (lane == 0) {
        sred[wave][0] = coord; sred[wave][1] = conf;
        sred[wave][2] = cls;   sred[wave][3] = nobj;
    }
    __syncthreads();
    if (tid == 0) {
        float4 o;
        o.x = sred[0][0] + sred[1][0] + sred[2][0] + sred[3][0];
        o.y = sred[0][1] + sred[1][1] + sred[2][1] + sred[3][1];
        o.z = sred[0][2] + sred[1][2] + sred[2][2] + sred[3][2];
        o.w = sred[0][3] + sred[1][3] + sred[2][3] + sred[3][3];
        part[blockIdx.x] = o;   // distinct address per block: no contention
    }
}

__global__ __launch_bounds__(256) void phobia_reduce_kernel(
    const float4* __restrict__ part, float* __restrict__ out)
{
    const int tid = threadIdx.x;
    float c0 = 0.f, c1 = 0.f, c2 = 0.f, c3 = 0.f;
    for (int i = tid; i < kBlocks; i += 256) {
        const float4 v = part[i];
        c0 += v.x; c1 += v.y; c2 += v.z; c3 += v.w;
    }
    #pragma unroll
    for (int off = 32; off >= 1; off >>= 1) {
        c0 += __shfl_down(c0, off);
        c1 += __shfl_down(c1, off);
        c2 += __shfl_down(c2, off);
        c3 += __shfl_down(c3, off);
    }
    __shared__ float sred[4][4];
    const int wave = tid >> 6;
    const int lane = tid & 63;
    if (lane == 0) {
        sred[wave][0] = c0; sred[wave][1] = c1;
        sred[wave][2] = c2; sred[wave][3] = c3;
    }
    __syncthreads();
    if (tid == 0) {
        const float coord = sred[0][0] + sred[1][0] + sred[2][0] + sred[3][0];
        const float conf  = sred[0][1] + sred[1][1] + sred[2][1] + sred[3][1];
        const float cls   = sred[0][2] + sred[1][2] + sred[2][2] + sred[3][2];
        const float nobj  = sred[0][3] + sred[1][3] + sred[2][3] + sred[3][3];
        out[0] = kLamCoord * (coord / (float)kB)
               + (conf / (float)kB)
               + cls / fmaxf(nobj, 1.f);
    }
}

extern "C" void kernel_launch(void* const* d_in, const int* in_sizes, int n_in,
                              void* d_out, int out_size, void* d_ws, size_t ws_size,
                              hipStream_t stream) {
    const float4* pred4 = (const float4*)d_in[0];
    const float4* tgt4  = (const float4*)d_in[1];
    float4* part = (float4*)d_ws;          // kBlocks * 16 B = 43,264 B
    float* out = (float*)d_out;

    phobia_main_kernel<<<kBlocks, 256, 0, stream>>>(pred4, tgt4, part);
    phobia_reduce_kernel<<<1, 256, 0, stream>>>(part, out);
}

// Round 5
// 27.171 us; speedup vs baseline: 5.7267x; 1.0041x over previous
//
#include <hip/hip_runtime.h>

// PhobiaLoss: YOLO-style loss over (B=256, 52, 52, 20) fp32 tensors -> scalar.
// Round 5: wave-autonomous staging. R4's block-wide __syncthreads forced a
// joint vmcnt(0) drain across all 4 waves and phase-locked load/compute
// bursts. Now each wave stages ITS OWN 64 cells into its own LDS slice via
// global_load_lds (linear dest), waits only its own vmcnt, gathers at
// lane*5+c (stride-5 quads, conflict-free), computes, reduces in-wave.
// No barrier until the trivial 4-way cross-wave partial sum at the end.
// LDS exactly 40960 B -> 4 blocks/CU (16 independent waves/CU).

constexpr int   kB        = 256;
constexpr int   kGrid     = 52;
constexpr int   kCells    = kB * kGrid * kGrid;   // 692224 = 2704 * 256 exactly
constexpr int   kBlocks   = kCells / 256;         // 2704
constexpr float kAlpha    = 0.25f;
constexpr float kLamCoord = 5.0f;

#define AS1(p) ((const __attribute__((address_space(1))) void*)(p))
#define AS3(p) ((__attribute__((address_space(3))) void*)(p))

__global__ __launch_bounds__(256) void phobia_main_kernel(
    const float4* __restrict__ pred4,
    const float4* __restrict__ tgt4,
    float4* __restrict__ part)   // part[block] = {coord, conf, cls, nobj}
{
    // Per-wave slices: lds[w][0..320) = pred, lds[w][320..640) = tgt.
    __shared__ float4 lds[4][640];   // 40960 B exactly

    const int tid  = threadIdx.x;
    const int wave = tid >> 6;
    const int lane = tid & 63;
    // This wave's 64 cells start at global float4 index:
    const size_t base4 = (size_t)blockIdx.x * 1280 + (size_t)wave * 320;

    // 10 direct global->LDS dwordx4 loads, all wave-local (1 KiB each, coalesced).
    #pragma unroll
    for (int k = 0; k < 5; ++k) {
        __builtin_amdgcn_global_load_lds(AS1(pred4 + base4 + k * 64 + lane),
                                         AS3(&lds[wave][k * 64]), 16, 0, 0);
        __builtin_amdgcn_global_load_lds(AS1(tgt4  + base4 + k * 64 + lane),
                                         AS3(&lds[wave][320 + k * 64]), 16, 0, 0);
    }
    // Wait for OWN loads only; no block barrier, waves slip freely.
    asm volatile("s_waitcnt vmcnt(0)" ::: "memory");
    __builtin_amdgcn_sched_barrier(0);

    // Gather this lane's cell: stride-5 float4s -> all 8 bank-quads, conflict-free.
    const float4 P0 = lds[wave][lane * 5 + 0], P1 = lds[wave][lane * 5 + 1];
    const float4 P2 = lds[wave][lane * 5 + 2], P3 = lds[wave][lane * 5 + 3];
    const float4 T0 = lds[wave][320 + lane * 5 + 0], T1 = lds[wave][320 + lane * 5 + 1];
    const float4 T2 = lds[wave][320 + lane * 5 + 2], T3 = lds[wave][320 + lane * 5 + 3];

    const float p[16] = {P0.x, P0.y, P0.z, P0.w,  P1.x, P1.y, P1.z, P1.w,
                         P2.x, P2.y, P2.z, P2.w,  P3.x, P3.y, P3.z, P3.w};
    const float t[16] = {T0.x, T0.y, T0.z, T0.w,  T1.x, T1.y, T1.z, T1.w,
                         T2.x, T2.y, T2.z, T2.w,  T3.x, T3.y, T3.z, T3.w};

    float coord = 0.f, conf = 0.f;
    float obj_count = 0.f;
    #pragma unroll
    for (int n = 0; n < 2; ++n) {
        const int b5    = n * 5;
        const float l   = p[b5 + 4];      // conf logit
        const float tc  = t[b5 + 4];      // conf target
        const float has = (tc > 0.5f) ? 1.f : 0.f;

        float sq = 0.f;
        #pragma unroll
        for (int k = 0; k < 4; ++k) {
            const float d = p[b5 + k] - t[b5 + k];
            sq += d * d;
        }
        coord += has * sq;

        // focal BCE on confidence
        const float ce = fmaxf(l, 0.f) - l * tc + log1pf(__expf(-fabsf(l)));
        const float s  = 1.f / (1.f + __expf(-l));
        const float pt = s * tc + (1.f - s) * (1.f - tc);
        const float at = kAlpha * tc + (1.f - kAlpha) * (1.f - tc);
        const float om = 1.f - pt;
        conf += at * om * om * ce;

        obj_count += has;
    }

    // class NLL: argmax of target channels 10..14 (strict > = first-max),
    // carry the matching pred logit so all register indices stay static.
    float bv = t[10], pv = p[10];
    if (t[11] > bv) { bv = t[11]; pv = p[11]; }
    if (t[12] > bv) { bv = t[12]; pv = p[12]; }
    if (t[13] > bv) { bv = t[13]; pv = p[13]; }
    if (t[14] > bv) { bv = t[14]; pv = p[14]; }

    const float m  = fmaxf(fmaxf(fmaxf(p[10], p[11]), fmaxf(p[12], p[13])), p[14]);
    const float se = __expf(p[10] - m) + __expf(p[11] - m) + __expf(p[12] - m)
                   + __expf(p[13] - m) + __expf(p[14] - m);
    float cls  = obj_count * (__logf(se) + m - pv);
    float nobj = obj_count;

    // Wave-level reduce (64 lanes, in-order SIMD)
    #pragma unroll
    for (int off = 32; off >= 1; off >>= 1) {
        coord += __shfl_down(coord, off);
        conf  += __shfl_down(conf,  off);
        cls   += __shfl_down(cls,   off);
        nobj  += __shfl_down(nobj,  off);
    }

    // Reuse this wave's own LDS slice for the partial (in-order within wave:
    // the write issues after every lane's gather reads have been consumed).
    if (lane == 0) {
        float4 o; o.x = coord; o.y = conf; o.z = cls; o.w = nobj;
        lds[wave][0] = o;
    }
    __syncthreads();   // only cross-wave sync; vmcnt already drained
    if (tid == 0) {
        const float4 a = lds[0][0], b = lds[1][0], c = lds[2][0], d = lds[3][0];
        float4 o;
        o.x = a.x + b.x + c.x + d.x;
        o.y = a.y + b.y + c.y + d.y;
        o.z = a.z + b.z + c.z + d.z;
        o.w = a.w + b.w + c.w + d.w;
        part[blockIdx.x] = o;   // distinct address per block: no contention
    }
}

__global__ __launch_bounds__(256) void phobia_reduce_kernel(
    const float4* __restrict__ part, float* __restrict__ out)
{
    const int tid = threadIdx.x;
    float c0 = 0.f, c1 = 0.f, c2 = 0.f, c3 = 0.f;
    for (int i = tid; i < kBlocks; i += 256) {
        const float4 v = part[i];
        c0 += v.x; c1 += v.y; c2 += v.z; c3 += v.w;
    }
    #pragma unroll
    for (int off = 32; off >= 1; off >>= 1) {
        c0 += __shfl_down(c0, off);
        c1 += __shfl_down(c1, off);
        c2 += __shfl_down(c2, off);
        c3 += __shfl_down(c3, off);
    }
    __shared__ float sred[4][4];
    const int wave = tid >> 6;
    const int lane = tid & 63;
    if (lane == 0) {
        sred[wave][0] = c0; sred[wave][1] = c1;
        sred[wave][2] = c2; sred[wave][3] = c3;
    }
    __syncthreads();
    if (tid == 0) {
        const float coord = sred[0][0] + sred[1][0] + sred[2][0] + sred[3][0];
        const float conf  = sred[0][1] + sred[1][1] + sred[2][1] + sred[3][1];
        const float cls   = sred[0][2] + sred[1][2] + sred[2][2] + sred[3][2];
        const float nobj  = sred[0][3] + sred[1][3] + sred[2][3] + sred[3][3];
        out[0] = kLamCoord * (coord / (float)kB)
               + (conf / (float)kB)
               + cls / fmaxf(nobj, 1.f);
    }
}

extern "C" void kernel_launch(void* const* d_in, const int* in_sizes, int n_in,
                              void* d_out, int out_size, void* d_ws, size_t ws_size,
                              hipStream_t stream) {
    const float4* pred4 = (const float4*)d_in[0];
    const float4* tgt4  = (const float4*)d_in[1];
    float4* part = (float4*)d_ws;          // kBlocks * 16 B = 43,264 B
    float* out = (float*)d_out;

    phobia_main_kernel<<<kBlocks, 256, 0, stream>>>(pred4, tgt4, part);
    phobia_reduce_kernel<<<1, 256, 0, stream>>>(part, out);
}